// Round 1
// baseline (3357.619 us; speedup 1.0000x reference)
//
#include <hip/hip_runtime.h>
#include <cstdint>
#include <cstddef>

#define B_ROWS 16384
#define K_DIM  1024
#define H_DIM  4096
#define O_DIM  4

#define BM 64
#define BN 64
#define BK 32
#define LDP 68   // padded leading dim: 68*4B = 272B = 17*16B -> float4-aligned rows, banks spread

// ---------------------------------------------------------------------------
// Kernel 1: cur1 = x @ W1^T + b1 ; spk1 = (cur1 > 1)  -> packed bits in d_ws
// f64 accumulation for exactness (spike comparator cannot tolerate fp32 noise).
// ---------------------------------------------------------------------------
__global__ __launch_bounds__(256) void snn_fc1(
    const float* __restrict__ x, const float* __restrict__ W1,
    const float* __restrict__ b1, uint32_t* __restrict__ spk_bits)
{
    __shared__ float As[BK][LDP];
    __shared__ float Bs[BK][LDP];
    __shared__ uint32_t bitbuf[BM][BN / 32];

    const int tid = threadIdx.x;
    const int m0 = blockIdx.y * BM;   // batch-row tile
    const int n0 = blockIdx.x * BN;   // hidden-unit tile

    const int rm = tid & 15;          // 16 row groups
    const int cn = tid >> 4;          // 16 col groups
    const int mf = 4 * rm;
    const int nf = 4 * cn;

    double acc[4][4];
#pragma unroll
    for (int i = 0; i < 4; ++i)
#pragma unroll
        for (int j = 0; j < 4; ++j) acc[i][j] = 0.0;

    const int sm  = tid >> 3;         // 0..31: row within half-tile
    const int skq = tid & 7;          // float4 index along k

    for (int kt = 0; kt < K_DIM / BK; ++kt) {
        const int k0 = kt * BK;
        // stage A (x) and B (W1) tiles, transposed into [k][m] layout
#pragma unroll
        for (int s = 0; s < 2; ++s) {
            const int m = sm + 32 * s;
            const float4 av = *reinterpret_cast<const float4*>(
                x + (size_t)(m0 + m) * K_DIM + k0 + 4 * skq);
            As[4 * skq + 0][m] = av.x; As[4 * skq + 1][m] = av.y;
            As[4 * skq + 2][m] = av.z; As[4 * skq + 3][m] = av.w;
            const float4 bv = *reinterpret_cast<const float4*>(
                W1 + (size_t)(n0 + m) * K_DIM + k0 + 4 * skq);
            Bs[4 * skq + 0][m] = bv.x; Bs[4 * skq + 1][m] = bv.y;
            Bs[4 * skq + 2][m] = bv.z; Bs[4 * skq + 3][m] = bv.w;
        }
        __syncthreads();
#pragma unroll
        for (int k = 0; k < BK; ++k) {
            const float4 af = *reinterpret_cast<const float4*>(&As[k][mf]);
            const float4 bf = *reinterpret_cast<const float4*>(&Bs[k][nf]);
            const double a0 = af.x, a1 = af.y, a2 = af.z, a3 = af.w;
            const double b0 = bf.x, b1v = bf.y, b2v = bf.z, b3 = bf.w;
            acc[0][0] = fma(a0, b0, acc[0][0]);  acc[0][1] = fma(a0, b1v, acc[0][1]);
            acc[0][2] = fma(a0, b2v, acc[0][2]); acc[0][3] = fma(a0, b3, acc[0][3]);
            acc[1][0] = fma(a1, b0, acc[1][0]);  acc[1][1] = fma(a1, b1v, acc[1][1]);
            acc[1][2] = fma(a1, b2v, acc[1][2]); acc[1][3] = fma(a1, b3, acc[1][3]);
            acc[2][0] = fma(a2, b0, acc[2][0]);  acc[2][1] = fma(a2, b1v, acc[2][1]);
            acc[2][2] = fma(a2, b2v, acc[2][2]); acc[2][3] = fma(a2, b3, acc[2][3]);
            acc[3][0] = fma(a3, b0, acc[3][0]);  acc[3][1] = fma(a3, b1v, acc[3][1]);
            acc[3][2] = fma(a3, b2v, acc[3][2]); acc[3][3] = fma(a3, b3, acc[3][3]);
        }
        __syncthreads();
    }

    // zero the bit tile
    if (tid < BM * (BN / 32)) {            // 128 words
        bitbuf[tid >> 1][tid & 1] = 0u;
    }
    __syncthreads();

    // bias + threshold -> bits
#pragma unroll
    for (int j = 0; j < 4; ++j) {
        const int n = nf + j;
        const double bias = (double)b1[n0 + n];
        const int w = n >> 5, bit = n & 31;
#pragma unroll
        for (int i = 0; i < 4; ++i) {
            const double cur = acc[i][j] + bias;   // mem1 = cur1 (mem_prev = 0)
            if (cur > 1.0) atomicOr(&bitbuf[mf + i][w], 1u << bit);
        }
    }
    __syncthreads();

    if (tid < 128) {
        const int r = tid >> 1, w = tid & 1;
        spk_bits[(size_t)(m0 + r) * (H_DIM / 32) + (n0 >> 5) + w] = bitbuf[r][w];
    }
}

// ---------------------------------------------------------------------------
// Kernel 2: cur2 = spk1 @ W2^T + b2 ; out = [mem2, spk2]
// One thread per (row, output). f64 accumulation (cheap, exact).
// ---------------------------------------------------------------------------
__global__ __launch_bounds__(256) void snn_fc2(
    const uint32_t* __restrict__ spk_bits, const float* __restrict__ W2,
    const float* __restrict__ b2, float* __restrict__ out)
{
    const int t = blockIdx.x * 256 + threadIdx.x;   // 0 .. 65535
    const int b = t >> 2;
    const int o = t & 3;
    const uint32_t* row = spk_bits + (size_t)b * (H_DIM / 32);
    const float* w = W2 + (size_t)o * H_DIM;

    double acc = (double)b2[o];
    for (int wd = 0; wd < H_DIM / 32; ++wd) {
        const uint32_t word = row[wd];
#pragma unroll
        for (int j = 0; j < 32; ++j) {
            acc += ((word >> j) & 1u) ? (double)w[32 * wd + j] : 0.0;
        }
    }
    out[t] = (float)acc;                                   // mem2
    out[B_ROWS * O_DIM + t] = (acc > 1.0) ? 1.0f : 0.0f;   // spk2
}

// ---------------------------------------------------------------------------
extern "C" void kernel_launch(void* const* d_in, const int* in_sizes, int n_in,
                              void* d_out, int out_size, void* d_ws, size_t ws_size,
                              hipStream_t stream) {
    const float* x  = (const float*)d_in[0];
    const float* W1 = (const float*)d_in[1];
    const float* b1 = (const float*)d_in[2];
    const float* W2 = (const float*)d_in[3];
    const float* b2 = (const float*)d_in[4];
    // d_in[5] = beta: unused (membranes start at 0, single timestep)

    float* out = (float*)d_out;
    uint32_t* bits = (uint32_t*)d_ws;   // 16384 * 128 * 4 B = 8 MB of spk1 bits

    dim3 g1(H_DIM / BN, B_ROWS / BM);   // (64, 256) = 16384 blocks
    snn_fc1<<<g1, 256, 0, stream>>>(x, W1, b1, bits);

    snn_fc2<<<(B_ROWS * O_DIM) / 256, 256, 0, stream>>>(bits, W2, b2, out);
}

// Round 2
// 1009.890 us; speedup vs baseline: 3.3247x; 3.3247x over previous
//
#include <hip/hip_runtime.h>
#include <cstdint>
#include <cstddef>

typedef unsigned short ushort_t;
typedef __attribute__((ext_vector_type(8))) short bf16x8;
typedef __attribute__((ext_vector_type(4))) float f32x4;

#define B_ROWS 16384
#define K_DIM  1024
#define H_DIM  4096
#define O_DIM  4
#define KP     3072            // packed K: per k, triples (h,h,l) . (h',l',h')
#define MARGIN 1e-3f
#define FLAG_CAP (1u<<20)

// fast-path ws layout (bytes)
#define OFF_XP   ((size_t)0)                 // 16384*3072*2 = 100663296
#define OFF_WP   ((size_t)100663296)         // 4096*3072*2  =  25165824
#define OFF_BITS ((size_t)125829120)         // 16384*128*4  =   8388608
#define OFF_CNT  ((size_t)134217728)         // 128 B
#define OFF_FLG  ((size_t)134217856)         // 1M * 4 B
#define WS_NEED  ((size_t)138412160)

#define GLD16(g, l) __builtin_amdgcn_global_load_lds(                         \
    (const __attribute__((address_space(1))) void*)(g),                       \
    (__attribute__((address_space(3))) void*)(l), 16, 0, 0)

__device__ __forceinline__ ushort_t bf16_rtn(float f) {
    uint32_t u = __float_as_uint(f);
    return (ushort_t)((u + 0x7fffu + ((u >> 16) & 1u)) >> 16);
}

// ---------------------------------------------------------------------------
// Split f32 row-major [rows][1024] into packed bf16 [rows][3072]:
// out[r][3k+0]=hi, [3k+1]=hi, [3k+2]=lo   (pairs with W's (hi',lo',hi'))
// ---------------------------------------------------------------------------
__global__ __launch_bounds__(256) void split3_hhl(
    const float* __restrict__ in, ushort_t* __restrict__ out, int nelem)
{
    const int stride = gridDim.x * blockDim.x;
    for (int idx = blockIdx.x * blockDim.x + threadIdx.x; idx < nelem; idx += stride) {
        const int r = idx >> 10, k = idx & 1023;
        const float f = in[idx];
        const ushort_t h = bf16_rtn(f);
        const float hf = __uint_as_float((uint32_t)h << 16);
        const ushort_t l = bf16_rtn(f - hf);
        const size_t o = (size_t)r * KP + 3 * (size_t)k;
        out[o] = h; out[o + 1] = h; out[o + 2] = l;
    }
}

__global__ __launch_bounds__(256) void split3_hlh(
    const float* __restrict__ in, ushort_t* __restrict__ out, int nelem)
{
    const int stride = gridDim.x * blockDim.x;
    for (int idx = blockIdx.x * blockDim.x + threadIdx.x; idx < nelem; idx += stride) {
        const int r = idx >> 10, k = idx & 1023;
        const float f = in[idx];
        const ushort_t h = bf16_rtn(f);
        const float hf = __uint_as_float((uint32_t)h << 16);
        const ushort_t l = bf16_rtn(f - hf);
        const size_t o = (size_t)r * KP + 3 * (size_t)k;
        out[o] = h; out[o + 1] = l; out[o + 2] = h;
    }
}

__global__ void zero_cnt(uint32_t* c) { if (threadIdx.x == 0) *c = 0; }

// ---------------------------------------------------------------------------
// fc1: bf16 MFMA GEMM (m97 structure), 128x128 tile, BK=32, K=3072.
// Epilogue: spike bits + near-boundary flags.
// ---------------------------------------------------------------------------
__global__ __launch_bounds__(256) void fc1_mfma(
    const ushort_t* __restrict__ Xp, const ushort_t* __restrict__ Wp,
    const float* __restrict__ b1, uint32_t* __restrict__ bits,
    uint32_t* __restrict__ cnt, uint32_t* __restrict__ flags)
{
    __shared__ __align__(16) ushort_t As[2][128 * 32];
    __shared__ __align__(16) ushort_t Bs[2][128 * 32];
    __shared__ uint32_t bitbuf[128 * 4];

    const int tid  = threadIdx.x;
    const int lane = tid & 63;
    const int w    = tid >> 6;                 // wave 0..3
    const int m0   = blockIdx.y * 128;
    const int n0   = blockIdx.x * 128;

    // staging: lane covers row w*16 + (lane>>2) (+64), 8-ushort chunk lane&3
    const int   srow   = w * 16 + (lane >> 2);
    const int   schunk = (lane & 3) * 8;
    const size_t gA0 = (size_t)(m0 + srow) * KP + schunk;
    const size_t gA1 = (size_t)(m0 + srow + 64) * KP + schunk;
    const size_t gB0 = (size_t)(n0 + srow) * KP + schunk;
    const size_t gB1 = (size_t)(n0 + srow + 64) * KP + schunk;

    auto stage = [&](int buf, int k0) {
        GLD16(Xp + gA0 + k0, &As[buf][w * 512]);
        GLD16(Xp + gA1 + k0, &As[buf][2048 + w * 512]);
        GLD16(Wp + gB0 + k0, &Bs[buf][w * 512]);
        GLD16(Wp + gB1 + k0, &Bs[buf][2048 + w * 512]);
    };

    f32x4 acc[4][4];
#pragma unroll
    for (int i = 0; i < 4; ++i)
#pragma unroll
        for (int j = 0; j < 4; ++j)
            acc[i][j] = (f32x4){0.f, 0.f, 0.f, 0.f};

    const int wr = (w >> 1) * 64;              // wave row offset in tile
    const int wc = (w & 1) * 64;               // wave col offset in tile
    const int frow = lane & 15;                // fragment row within 16
    const int fk   = (lane >> 4) * 8;          // k-offset within 32

    stage(0, 0);
    int buf = 0;
    for (int t = 0; t < KP / 32; ++t) {
        __syncthreads();                        // drains stage(t)
        if (t + 1 < KP / 32) stage(buf ^ 1, (t + 1) * 32);
        bf16x8 a[4], b[4];
#pragma unroll
        for (int i = 0; i < 4; ++i) {
            a[i] = *reinterpret_cast<const bf16x8*>(
                &As[buf][(wr + i * 16 + frow) * 32 + fk]);
            b[i] = *reinterpret_cast<const bf16x8*>(
                &Bs[buf][(wc + i * 16 + frow) * 32 + fk]);
        }
#pragma unroll
        for (int i = 0; i < 4; ++i)
#pragma unroll
            for (int j = 0; j < 4; ++j)
                acc[i][j] = __builtin_amdgcn_mfma_f32_16x16x32_bf16(
                    a[i], b[j], acc[i][j], 0, 0, 0);
        buf ^= 1;
    }

    // epilogue: bits + flags
    bitbuf[tid] = 0u; bitbuf[tid + 256] = 0u;
    __syncthreads();

    float bcol[4];
#pragma unroll
    for (int j = 0; j < 4; ++j) bcol[j] = b1[n0 + wc + j * 16 + (lane & 15)];

#pragma unroll
    for (int i = 0; i < 4; ++i) {
#pragma unroll
        for (int j = 0; j < 4; ++j) {
            const int col_l = wc + j * 16 + (lane & 15);
#pragma unroll
            for (int r = 0; r < 4; ++r) {
                const int row_l = wr + i * 16 + ((lane >> 4) << 2) + r;
                const float cur = acc[i][j][r] + bcol[j];
                if (cur > 1.0f)
                    atomicOr(&bitbuf[row_l * 4 + (col_l >> 5)], 1u << (col_l & 31));
                if (fabsf(cur - 1.0f) < MARGIN) {
                    uint32_t ix = atomicAdd(cnt, 1u);
                    if (ix < FLAG_CAP)
                        flags[ix] = ((uint32_t)(m0 + row_l) << 12) | (uint32_t)(n0 + col_l);
                }
            }
        }
    }
    __syncthreads();

#pragma unroll
    for (int s = 0; s < 2; ++s) {
        const int widx = tid + s * 256;
        const int row = widx >> 2, c = widx & 3;
        bits[(size_t)(m0 + row) * 128 + blockIdx.x * 4 + c] = bitbuf[widx];
    }
}

// ---------------------------------------------------------------------------
// refine: exact f64 dot for flagged (row,col); fix the spike bit.
// ---------------------------------------------------------------------------
__global__ __launch_bounds__(256) void refine(
    const float* __restrict__ x, const float* __restrict__ W1,
    const float* __restrict__ b1, const uint32_t* __restrict__ cnt,
    const uint32_t* __restrict__ flags, uint32_t* __restrict__ bits)
{
    const int lane = threadIdx.x & 63;
    const int wave = (blockIdx.x * 256 + threadIdx.x) >> 6;
    const int nw   = (gridDim.x * 256) >> 6;
    uint32_t n = *cnt; if (n > FLAG_CAP) n = FLAG_CAP;

    for (uint32_t f = wave; f < n; f += nw) {
        const uint32_t e = flags[f];
        const int row = e >> 12, col = e & 4095;
        const float4* xr = (const float4*)(x  + (size_t)row * K_DIM);
        const float4* wr = (const float4*)(W1 + (size_t)col * K_DIM);
        double s = 0.0;
#pragma unroll
        for (int i = 0; i < 4; ++i) {
            const float4 xa = xr[lane + i * 64];
            const float4 wa = wr[lane + i * 64];
            s = fma((double)xa.x, (double)wa.x, s);
            s = fma((double)xa.y, (double)wa.y, s);
            s = fma((double)xa.z, (double)wa.z, s);
            s = fma((double)xa.w, (double)wa.w, s);
        }
        for (int off = 32; off; off >>= 1) s += __shfl_down(s, off, 64);
        if (lane == 0) {
            const double cur = s + (double)b1[col];
            uint32_t* word = &bits[(size_t)row * 128 + (col >> 5)];
            const uint32_t mask = 1u << (col & 31);
            if (cur > 1.0) atomicOr(word, mask);
            else           atomicAnd(word, ~mask);
        }
    }
}

// ---------------------------------------------------------------------------
// Fallback exact-f64 fc1 (round-1 kernel)
// ---------------------------------------------------------------------------
#define BM 64
#define BN 64
#define BK 32
__global__ __launch_bounds__(256) void snn_fc1(
    const float* __restrict__ x, const float* __restrict__ W1,
    const float* __restrict__ b1, uint32_t* __restrict__ spk_bits)
{
    __shared__ float As[BK][68];
    __shared__ float Bs[BK][68];
    __shared__ uint32_t bitbuf[BM][BN / 32];

    const int tid = threadIdx.x;
    const int m0 = blockIdx.y * BM;
    const int n0 = blockIdx.x * BN;
    const int rm = tid & 15, cn = tid >> 4;
    const int mf = 4 * rm, nf = 4 * cn;

    double acc[4][4];
#pragma unroll
    for (int i = 0; i < 4; ++i)
#pragma unroll
        for (int j = 0; j < 4; ++j) acc[i][j] = 0.0;

    const int sm = tid >> 3, skq = tid & 7;
    for (int kt = 0; kt < K_DIM / BK; ++kt) {
        const int k0 = kt * BK;
#pragma unroll
        for (int s = 0; s < 2; ++s) {
            const int m = sm + 32 * s;
            const float4 av = *reinterpret_cast<const float4*>(
                x + (size_t)(m0 + m) * K_DIM + k0 + 4 * skq);
            As[4 * skq + 0][m] = av.x; As[4 * skq + 1][m] = av.y;
            As[4 * skq + 2][m] = av.z; As[4 * skq + 3][m] = av.w;
            const float4 bv = *reinterpret_cast<const float4*>(
                W1 + (size_t)(n0 + m) * K_DIM + k0 + 4 * skq);
            Bs[4 * skq + 0][m] = bv.x; Bs[4 * skq + 1][m] = bv.y;
            Bs[4 * skq + 2][m] = bv.z; Bs[4 * skq + 3][m] = bv.w;
        }
        __syncthreads();
#pragma unroll
        for (int k = 0; k < BK; ++k) {
            const float4 af = *reinterpret_cast<const float4*>(&As[k][mf]);
            const float4 bf = *reinterpret_cast<const float4*>(&Bs[k][nf]);
            const double a0 = af.x, a1 = af.y, a2 = af.z, a3 = af.w;
            const double b0 = bf.x, b1v = bf.y, b2v = bf.z, b3 = bf.w;
            acc[0][0] = fma(a0, b0, acc[0][0]);  acc[0][1] = fma(a0, b1v, acc[0][1]);
            acc[0][2] = fma(a0, b2v, acc[0][2]); acc[0][3] = fma(a0, b3, acc[0][3]);
            acc[1][0] = fma(a1, b0, acc[1][0]);  acc[1][1] = fma(a1, b1v, acc[1][1]);
            acc[1][2] = fma(a1, b2v, acc[1][2]); acc[1][3] = fma(a1, b3, acc[1][3]);
            acc[2][0] = fma(a2, b0, acc[2][0]);  acc[2][1] = fma(a2, b1v, acc[2][1]);
            acc[2][2] = fma(a2, b2v, acc[2][2]); acc[2][3] = fma(a2, b3, acc[2][3]);
            acc[3][0] = fma(a3, b0, acc[3][0]);  acc[3][1] = fma(a3, b1v, acc[3][1]);
            acc[3][2] = fma(a3, b2v, acc[3][2]); acc[3][3] = fma(a3, b3, acc[3][3]);
        }
        __syncthreads();
    }

    if (tid < BM * (BN / 32)) bitbuf[tid >> 1][tid & 1] = 0u;
    __syncthreads();
#pragma unroll
    for (int j = 0; j < 4; ++j) {
        const int n = nf + j;
        const double bias = (double)b1[n0 + n];
        const int wd = n >> 5, bit = n & 31;
#pragma unroll
        for (int i = 0; i < 4; ++i) {
            const double cur = acc[i][j] + bias;
            if (cur > 1.0) atomicOr(&bitbuf[mf + i][wd], 1u << bit);
        }
    }
    __syncthreads();
    if (tid < 128) {
        const int r = tid >> 1, wd = tid & 1;
        spk_bits[(size_t)(m0 + r) * (H_DIM / 32) + (n0 >> 5) + wd] = bitbuf[r][wd];
    }
}

// ---------------------------------------------------------------------------
// fc2: cur2 = spk1 @ W2^T + b2 -> [mem2, spk2]
// ---------------------------------------------------------------------------
__global__ __launch_bounds__(256) void snn_fc2(
    const uint32_t* __restrict__ spk_bits, const float* __restrict__ W2,
    const float* __restrict__ b2, float* __restrict__ out)
{
    const int t = blockIdx.x * 256 + threadIdx.x;
    const int b = t >> 2;
    const int o = t & 3;
    const uint32_t* row = spk_bits + (size_t)b * (H_DIM / 32);
    const float* w = W2 + (size_t)o * H_DIM;

    double acc = (double)b2[o];
    for (int wd = 0; wd < H_DIM / 32; ++wd) {
        const uint32_t word = row[wd];
#pragma unroll
        for (int j = 0; j < 32; ++j) {
            acc += ((word >> j) & 1u) ? (double)w[32 * wd + j] : 0.0;
        }
    }
    out[t] = (float)acc;
    out[B_ROWS * O_DIM + t] = (acc > 1.0) ? 1.0f : 0.0f;
}

// ---------------------------------------------------------------------------
extern "C" void kernel_launch(void* const* d_in, const int* in_sizes, int n_in,
                              void* d_out, int out_size, void* d_ws, size_t ws_size,
                              hipStream_t stream) {
    const float* x  = (const float*)d_in[0];
    const float* W1 = (const float*)d_in[1];
    const float* b1 = (const float*)d_in[2];
    const float* W2 = (const float*)d_in[3];
    const float* b2 = (const float*)d_in[4];
    float* out = (float*)d_out;
    char* ws = (char*)d_ws;

    if (ws_size >= WS_NEED) {
        ushort_t* Xp   = (ushort_t*)(ws + OFF_XP);
        ushort_t* Wp   = (ushort_t*)(ws + OFF_WP);
        uint32_t* bits = (uint32_t*)(ws + OFF_BITS);
        uint32_t* cnt  = (uint32_t*)(ws + OFF_CNT);
        uint32_t* flg  = (uint32_t*)(ws + OFF_FLG);

        zero_cnt<<<1, 64, 0, stream>>>(cnt);
        split3_hhl<<<8192, 256, 0, stream>>>(x,  Xp, B_ROWS * K_DIM);
        split3_hlh<<<4096, 256, 0, stream>>>(W1, Wp, H_DIM * K_DIM);
        fc1_mfma<<<dim3(H_DIM / 128, B_ROWS / 128), 256, 0, stream>>>(
            Xp, Wp, b1, bits, cnt, flg);
        refine<<<1024, 256, 0, stream>>>(x, W1, b1, cnt, flg, bits);
        snn_fc2<<<(B_ROWS * O_DIM) / 256, 256, 0, stream>>>(bits, W2, b2, out);
    } else {
        uint32_t* bits = (uint32_t*)ws;
        dim3 g1(H_DIM / BN, B_ROWS / BM);
        snn_fc1<<<g1, 256, 0, stream>>>(x, W1, b1, bits);
        snn_fc2<<<(B_ROWS * O_DIM) / 256, 256, 0, stream>>>(bits, W2, b2, out);
    }
}